// Round 1
// baseline (2763.866 us; speedup 1.0000x reference)
//
#include <hip/hip_runtime.h>
#include <cstdint>

typedef __attribute__((ext_vector_type(4))) float floatx4;
typedef __attribute__((ext_vector_type(8))) __bf16 bf16x8;
typedef __attribute__((ext_vector_type(4))) unsigned short ushortx4;

#define NN 8192
#define BB 256
#define SELU_SCALE 1.0507009873554805f
#define SELU_SA    1.7580993408473766f   /* scale*alpha */

// round-to-nearest-even f32 -> bf16 bits
__device__ __forceinline__ unsigned short f2bf(float f) {
  unsigned u = __builtin_bit_cast(unsigned, f);
  u += 0x7FFFu + ((u >> 16) & 1u);
  return (unsigned short)(u >> 16);
}

// async global->LDS, 16B per lane; LDS dest must be wave-uniform base + lane*16
__device__ __forceinline__ void load16_lds(const void* g, void* l) {
  __builtin_amdgcn_global_load_lds((__attribute__((address_space(1))) void*)(g),
                                   (__attribute__((address_space(3))) void*)(l),
                                   16, 0, 0);
}

__global__ void zero_f32(float* __restrict__ p) {
  const int i = blockIdx.x * blockDim.x + threadIdx.x;
  ((floatx4*)p)[i] = floatx4{0.f, 0.f, 0.f, 0.f};
}

// x [256, 8192] -> xT [8192, 256]
__global__ void transpose_x(const float* __restrict__ x, float* __restrict__ xT) {
  __shared__ float tile[32][33];
  const int n0 = blockIdx.x * 32;
  const int b0 = blockIdx.y * 32;
  const int tn = threadIdx.x & 31;
  const int tb = threadIdx.x >> 5;
#pragma unroll
  for (int i = 0; i < 4; i++)
    tile[tb + i * 8][tn] = x[(b0 + tb + i * 8) * NN + n0 + tn];
  __syncthreads();
  const int tb2 = threadIdx.x & 31;
  const int tn2 = threadIdx.x >> 5;
#pragma unroll
  for (int i = 0; i < 4; i++)
    xT[(n0 + tn2 + i * 8) * BB + b0 + tb2] = tile[tb2][tn2 + i * 8];
}

// one wave per nnz k: acc[b][rows[k]] += vals[k] * x[b][cols[k]]  (acc layout [B, N])
__global__ void spmv_scatter(const float* __restrict__ xT, const float* __restrict__ vals,
                             const int* __restrict__ rows, const int* __restrict__ cols,
                             float* __restrict__ acc, int nnz) {
  const int k = blockIdx.x * 4 + (threadIdx.x >> 6);
  if (k >= nnz) return;
  const int lane = threadIdx.x & 63;
  const float v = vals[k];
  const int r = rows[k];
  const int c = cols[k];
  const floatx4 xv = *(const floatx4*)(xT + c * BB + lane * 4);
#pragma unroll
  for (int j = 0; j < 4; j++)
    atomicAdd(acc + (lane * 4 + j) * NN + r, v * xv[j]);
}

// y[b,n] = bf16(bc[n] + acc[b,n]*flag[n])
__global__ void build_y(const float* __restrict__ acc, const float* __restrict__ bc,
                        const float* __restrict__ flag, unsigned short* __restrict__ y) {
  const int i = blockIdx.x * blockDim.x + threadIdx.x;
  const int base = i * 4;
  const int n = base & (NN - 1);
  const floatx4 a = ((const floatx4*)acc)[i];
  const floatx4 bcv = *(const floatx4*)(bc + n);
  const floatx4 fv = *(const floatx4*)(flag + n);
  ushortx4 o;
#pragma unroll
  for (int j = 0; j < 4; j++) o[j] = f2bf(bcv[j] + a[j] * fv[j]);
  *(ushortx4*)(y + base) = o;
}

// C[m,n] = sum_k A[m,k]*W[n,k]; A bf16 [256,8192], W f32 [8192,8192] row-major.
// BM=128, BN=32, BK=32; grid 512 (2 blocks/CU); block 256 = 4 waves;
// wave (wm,wn): rows wm*64..+63 (4 m-frags), cols wn*16..+15 (1 n-frag).
// MODE 0: h = selu(C + bias) -> bf16.  MODE 1: out = bc + (C + bias)*flag -> f32.
template <int MODE>
__global__ __launch_bounds__(256, 2) void gemm_bt(
    const unsigned short* __restrict__ A, const float* __restrict__ W,
    const float* __restrict__ bias, const float* __restrict__ bc,
    const float* __restrict__ flag, unsigned short* __restrict__ hout,
    float* __restrict__ fout) {
  __shared__ unsigned short lA[128 * 32];  // [m][k], 64B rows
  __shared__ unsigned short lB[32 * 32];   // [n][k]
  const int t = threadIdx.x;
  const int lane = t & 63;
  const int wave = t >> 6;
  const int wm = wave >> 1, wn = wave & 1;
  const int nt = blockIdx.x >> 1, mt = blockIdx.x & 1;  // bx pairs share the W slab (LLC reuse)
  const int m0 = mt * 128, n0 = nt * 32;

  floatx4 acc[4];
#pragma unroll
  for (int i = 0; i < 4; i++) acc[i] = floatx4{0.f, 0.f, 0.f, 0.f};

  // A staging: 2 issues of 4KB; lds offset = t*16B (wave-uniform base + lane*16)
  const int arow = t >> 2, ach = t & 3;
  const unsigned short* ag = A + (m0 + arow) * NN + ach * 8;
  unsigned short* al = lA + arow * 32 + ach * 8;
  // W staging: float4 load + cvt + 8B ds_write
  const int brow = t >> 3, bch = t & 7;
  const float* wg = W + (n0 + brow) * NN + bch * 4;
  unsigned short* bl = lB + brow * 32 + bch * 4;

  const int quad = lane >> 4, lrow = lane & 15;
  const unsigned short* lbase_a = lA + (wm * 64 + lrow) * 32 + quad * 8;
  const unsigned short* lbase_b = lB + (wn * 16 + lrow) * 32 + quad * 8;

  for (int k0 = 0; k0 < NN; k0 += 32) {
    __syncthreads();  // prior iter's ds_reads done before overwrite
    load16_lds(ag + k0, al);
    load16_lds(ag + 64 * NN + k0, al + 64 * 32);
    const floatx4 wv = *(const floatx4*)(wg + k0);
    ushortx4 wp;
#pragma unroll
    for (int j = 0; j < 4; j++) wp[j] = f2bf(wv[j]);
    *(ushortx4*)bl = wp;
    __syncthreads();  // drains vmcnt (global_load_lds) + lgkm (ds_write)

    const bf16x8 bfrag = *(const bf16x8*)lbase_b;
#pragma unroll
    for (int mf = 0; mf < 4; mf++) {
      const bf16x8 afrag = *(const bf16x8*)(lbase_a + mf * 16 * 32);
      acc[mf] = __builtin_amdgcn_mfma_f32_16x16x32_bf16(afrag, bfrag, acc[mf], 0, 0, 0);
    }
  }

  // C/D mapping (m89/m91-verified): n = n_off + (lane&15), m = m_off + (lane>>4)*4 + reg
  const int n = n0 + wn * 16 + lrow;
  const float bn = bias[n];
  if (MODE == 0) {
#pragma unroll
    for (int mf = 0; mf < 4; mf++) {
      const int mb = m0 + wm * 64 + mf * 16 + quad * 4;
#pragma unroll
      for (int r = 0; r < 4; r++) {
        float v = acc[mf][r] + bn;
        v = v > 0.f ? SELU_SCALE * v : SELU_SA * (__expf(v) - 1.f);
        hout[(mb + r) * NN + n] = f2bf(v);
      }
    }
  } else {
    const float bcn = bc[n], fn = flag[n];
#pragma unroll
    for (int mf = 0; mf < 4; mf++) {
      const int mb = m0 + wm * 64 + mf * 16 + quad * 4;
#pragma unroll
      for (int r = 0; r < 4; r++) {
        fout[(mb + r) * NN + n] = bcn + (acc[mf][r] + bn) * fn;
      }
    }
  }
}

extern "C" void kernel_launch(void* const* d_in, const int* in_sizes, int n_in,
                              void* d_out, int out_size, void* d_ws, size_t ws_size,
                              hipStream_t stream) {
  const float* x    = (const float*)d_in[0];
  const float* vals = (const float*)d_in[1];
  const float* bc   = (const float*)d_in[2];
  const float* flag = (const float*)d_in[3];
  const float* W1   = (const float*)d_in[4];
  const float* b1   = (const float*)d_in[5];
  const float* W2   = (const float*)d_in[6];
  const float* b2   = (const float*)d_in[7];
  const float* W3   = (const float*)d_in[8];
  const float* b3   = (const float*)d_in[9];
  const int* rows   = (const int*)d_in[10];
  const int* cols   = (const int*)d_in[11];
  float* out = (float*)d_out;
  const int nnz = in_sizes[1];

  // ws layout (20 MB):
  //   [0,8M)   acc f32 [256,8192]   -> later reused as h2 bf16 (acc dead after build_y)
  //   [8M,16M) xT  f32 [8192,256]   -> later reused as h1 bf16 (xT dead after scatter)
  //   [16M,20M) y  bf16 [256,8192]
  char* ws = (char*)d_ws;
  float* acc = (float*)(ws);
  float* xT  = (float*)(ws + (8u << 20));
  unsigned short* y  = (unsigned short*)(ws + (16u << 20));
  unsigned short* h1 = (unsigned short*)(ws + (8u << 20));
  unsigned short* h2 = (unsigned short*)(ws);

  zero_f32<<<(BB * NN) / (256 * 4), 256, 0, stream>>>(acc);
  transpose_x<<<dim3(NN / 32, BB / 32), 256, 0, stream>>>(x, xT);
  spmv_scatter<<<(nnz + 3) / 4, 256, 0, stream>>>(xT, vals, rows, cols, acc, nnz);
  build_y<<<(BB * NN) / (256 * 4), 256, 0, stream>>>(acc, bc, flag, y);

  gemm_bt<0><<<512, 256, 0, stream>>>(y,  W1, b1, nullptr, nullptr, h1, nullptr);
  gemm_bt<0><<<512, 256, 0, stream>>>(h1, W2, b2, nullptr, nullptr, h2, nullptr);
  gemm_bt<1><<<512, 256, 0, stream>>>(h2, W3, b3, bc, flag, nullptr, out);
}